// Round 11
// baseline (867.890 us; speedup 1.0000x reference)
//
#include <hip/hip_runtime.h>
#include <hip/hip_bf16.h>

#define S_LEN 2048
#define HIDN  4096
#define NH    32
#define HD    128

typedef __attribute__((ext_vector_type(8))) __bf16 bf16x8;
typedef __attribute__((ext_vector_type(4))) float  f32x4;
typedef __attribute__((ext_vector_type(16))) float f32x16;
typedef unsigned short u16;

__device__ __forceinline__ float bf2f(u16 u) {
  unsigned v = ((unsigned)u) << 16;
  return __builtin_bit_cast(float, v);
}
__device__ __forceinline__ u16 f2bf(float f) {
  unsigned u = __builtin_bit_cast(unsigned, f);
  u += 0x7FFFu + ((u >> 16) & 1u);
  return (u16)(u >> 16);
}
__device__ __forceinline__ float fexp2(float x) {   // 2^x, single v_exp_f32
  float r; asm("v_exp_f32 %0, %1" : "=v"(r) : "v"(x)); return r;
}
__device__ __forceinline__ void gload16(const void* g, void* l) {
  __builtin_amdgcn_global_load_lds((const __attribute__((address_space(1))) void*)g,
                                   (__attribute__((address_space(3))) void*)l, 16, 0, 0);
}
#define MFMA16(a, b, c) __builtin_amdgcn_mfma_f32_16x16x32_bf16(a, b, c, 0, 0, 0)
#define MFMA32(a, b, c) __builtin_amdgcn_mfma_f32_32x32x16_bf16(a, b, c, 0, 0, 0)

// ---------------- prep kernels ----------------

// f32 [R][C] -> bf16 [C][R]
__global__ void transpose_cast(const float* __restrict__ in, u16* __restrict__ out,
                               int R, int C) {
  __shared__ float t[32][33];
  const int c0 = blockIdx.x * 32, r0 = blockIdx.y * 32;
  const int tx = threadIdx.x, ty = threadIdx.y;
#pragma unroll
  for (int i = 0; i < 4; ++i)
    t[ty + i * 8][tx] = in[(size_t)(r0 + ty + i * 8) * C + c0 + tx];
  __syncthreads();
#pragma unroll
  for (int i = 0; i < 4; ++i)
    out[(size_t)(c0 + ty + i * 8) * R + r0 + tx] = f2bf(t[tx][ty + i * 8]);
}

struct u16x4s { u16 x, y, z, w; };

__global__ void cast_bf16_k(const float* __restrict__ in, u16* __restrict__ out, int n4) {
  int i = blockIdx.x * 256 + threadIdx.x;
  if (i < n4) {
    float4 v = ((const float4*)in)[i];
    u16x4s o;
    o.x = f2bf(v.x); o.y = f2bf(v.y); o.z = f2bf(v.z); o.w = f2bf(v.w);
    ((u16x4s*)out)[i] = o;
  }
}

__global__ void rope_table_k(const int* __restrict__ pos, float* __restrict__ cs,
                             float* __restrict__ sn) {
  int idx = blockIdx.x * 256 + threadIdx.x;   // S_LEN*64 total
  int s = idx >> 6, d = idx & 63;
  float inv = exp2f((-(float)d / 64.f) * 13.287712379549449f); // log2(10000)
  float ang = (float)pos[s] * inv;
  cs[idx] = cosf(ang);
  sn[idx] = sinf(ang);
}

// qkv bf16 [B*S][3*HIDN] -> roped Q,K bf16 [B,H,S,D]
// Q gets scale/sqrt(D) * log2(e) folded in (softmax runs in exp2 domain).
__global__ void rope_apply(const u16* __restrict__ qkv, const float* __restrict__ cs,
                           const float* __restrict__ sn, u16* __restrict__ Q,
                           u16* __restrict__ K) {
  const int row = blockIdx.x;            // b*S + s
  const int b = row >> 11, s = row & 2047;
  const u16* src = qkv + (size_t)row * (3 * HIDN);
#pragma unroll
  for (int it = 0; it < 2; ++it) {
    int idx = it * 256 + threadIdx.x;    // 512 = 2 which * 32 h * 8 groups
    int which = idx >> 8, h = (idx >> 3) & 31, d0 = (idx & 7) * 8;
    const u16* sp = src + which * HIDN + h * HD + d0;
    bf16x8 v1 = *(const bf16x8*)sp;
    bf16x8 v2 = *(const bf16x8*)(sp + 64);
    float4 c0 = *(const float4*)&cs[s * 64 + d0];
    float4 c1 = *(const float4*)&cs[s * 64 + d0 + 4];
    float4 s0 = *(const float4*)&sn[s * 64 + d0];
    float4 s1 = *(const float4*)&sn[s * 64 + d0 + 4];
    const float sc = which ? 1.0f : 0.12751743f;  // (1/sqrt(128))*log2(e) in Q
    bf16x8 r1, r2;
#pragma unroll
    for (int j = 0; j < 8; ++j) {
      float x1 = (float)v1[j], x2 = (float)v2[j];
      float cj = (j < 4) ? c0[j & 3] : c1[j & 3];
      float sj = (j < 4) ? s0[j & 3] : s1[j & 3];
      r1[j] = (__bf16)((x1 * cj - x2 * sj) * sc);
      r2[j] = (__bf16)((x2 * cj + x1 * sj) * sc);
    }
    u16* dst = (which ? K : Q) + ((size_t)(b * NH + h) * S_LEN + s) * HD + d0;
    *(bf16x8*)dst = r1;
    *(bf16x8*)(dst + 64) = r2;
  }
}

// V part of qkv -> Vt bf16 [B,H,D,S]
__global__ void v_transpose(const u16* __restrict__ qkv, u16* __restrict__ Vt) {
  __shared__ u16 t[32][33];
  const int bh = blockIdx.z;
  const int b = bh >> 5, h = bh & 31;
  const int s0 = blockIdx.x * 32, d0 = blockIdx.y * 32;
  const int tx = threadIdx.x, ty = threadIdx.y;
  const u16* src = qkv + (size_t)(b * S_LEN + s0) * (3 * HIDN) + 2 * HIDN + h * HD + d0;
#pragma unroll
  for (int i = 0; i < 4; ++i)
    t[ty + i * 8][tx] = src[(size_t)(ty + i * 8) * (3 * HIDN) + tx];
  __syncthreads();
  u16* dst = Vt + ((size_t)bh * HD + d0) * S_LEN + s0;
#pragma unroll
  for (int i = 0; i < 4; ++i)
    dst[(size_t)(ty + i * 8) * S_LEN + tx] = t[tx][ty + i * 8];
}

// ---------------- 256x256 4-phase GEMM (32x32x16 MFMA) ----------------
// C[M][N] = A[M][K] * Bt[N][K]^T + bias. 512 threads = 8 waves (2M x 4N),
// per-wave output 128x64 as 4x2 frags of 32x32. BK=64; LDS/staging/sync
// skeleton identical to the proven R5 schedule (race audit unchanged).
// 32x32x16 path: µbench 2382-2495 TF vs 2075 for 16x16x32 (+15% pipe rate),
// half the MFMA instruction count; LDS bytes identical; fragment reads stay
// slot-uniform -> conflict-free.
// Operand layout: lane l -> row=l&31, k=(l>>5)*8+j (8 contiguous k).
// C/D: col=lane&31, row=(reg&3)+8*(reg>>2)+4*(lane>>5)  [m74/m101 verified].
template <int OUT_BF16>
__global__ __launch_bounds__(512) void gemm256(
    const u16* __restrict__ A, const u16* __restrict__ Bt,
    const float* __restrict__ bias, void* __restrict__ Cv,
    int M, int N, int K, int nbm) {
  __shared__ alignas(16) u16 lds[2][2][2][128 * 64];
  const int tid = threadIdx.x;
  const int cpx = gridDim.x >> 3;
  const int swz = (blockIdx.x & 7) * cpx + (blockIdx.x >> 3);   // bijective (nb%8==0)
  const int bm = (swz % nbm) * 256, bn = (swz / nbm) * 256;     // bm fastest: B reuse in L2
  const int w = tid >> 6, l = tid & 63;
  const int wm = w >> 2, wn = w & 3;
  const int l31 = l & 31, lk8 = (l >> 5) * 8;    // frag row, frag k-offset
  const int rswz = (l & 7) * 8;                  // read-side XOR (u16 units)
  const int rl = tid >> 3;                        // staging row (per 8 threads)
  const int sl = (tid & 7) ^ ((tid >> 3) & 7);    // staging source slot (inverse swz)
  const u16* Ap = A + (size_t)bm * K;
  const u16* Bp = Bt + (size_t)bn * K;

#define STG(buf, ab, half, kt) do { \
    const u16* s_ = (ab ? Bp : Ap) + (size_t)((half) * 128 + rl) * K + (kt) * 64 + sl * 8; \
    u16* d_ = &lds[buf][ab][half][tid * 8]; \
    gload16(s_, d_); \
    gload16(s_ + (size_t)64 * K, d_ + 4096); \
  } while (0)

  f32x16 acc[4][2] = {};
  // prologue: K-tile 0 complete + K-tile 1 A halves = 12 loads
  STG(0, 0, 0, 0); STG(0, 0, 1, 0); STG(0, 1, 0, 0); STG(0, 1, 1, 0);
  STG(1, 0, 0, 1); STG(1, 0, 1, 1);
  asm volatile("s_waitcnt vmcnt(4)" ::: "memory");   // K-tile 0 landed
  __builtin_amdgcn_s_barrier();

  const int NT = K >> 6;
  bf16x8 a01[2][4], a23[2][4], bfv[4];
  for (int t = 0; t < NT; ++t) {
    const int buf = t & 1;
    const u16* Al = &lds[buf][0][wm][0];
    const u16* Bl = &lds[buf][1][wn >> 1][0];
    const int brow = (wn & 1) * 64;
    // ---------- phase 1: A(mi0-1) + B(ni0) reads; MFMA mi0-1 x ni0 ----------
#pragma unroll
    for (int mi = 0; mi < 2; ++mi)
#pragma unroll
      for (int ks = 0; ks < 4; ++ks)
        a01[mi][ks] = *(const bf16x8*)&Al[(mi * 32 + l31) * 64 + ((ks * 16 + lk8) ^ rswz)];
#pragma unroll
    for (int ks = 0; ks < 4; ++ks)
      bfv[ks] = *(const bf16x8*)&Bl[(brow + l31) * 64 + ((ks * 16 + lk8) ^ rswz)];
    if (t + 1 < NT) STG(buf ^ 1, 1, 0, t + 1);
    __builtin_amdgcn_s_barrier();
    __builtin_amdgcn_s_setprio(1);
#pragma unroll
    for (int mi = 0; mi < 2; ++mi)
#pragma unroll
      for (int ks = 0; ks < 4; ++ks)
        acc[mi][0] = MFMA32(a01[mi][ks], bfv[ks], acc[mi][0]);
    __builtin_amdgcn_s_setprio(0);
    __builtin_amdgcn_s_barrier();
    // ---------- phase 2: A(mi2-3) reads; MFMA mi2-3 x ni0 ----------
#pragma unroll
    for (int mi = 0; mi < 2; ++mi)
#pragma unroll
      for (int ks = 0; ks < 4; ++ks)
        a23[mi][ks] = *(const bf16x8*)&Al[((mi + 2) * 32 + l31) * 64 + ((ks * 16 + lk8) ^ rswz)];
    if (t + 1 < NT) STG(buf ^ 1, 1, 1, t + 1);
    __builtin_amdgcn_s_barrier();
    __builtin_amdgcn_s_setprio(1);
#pragma unroll
    for (int mi = 0; mi < 2; ++mi)
#pragma unroll
      for (int ks = 0; ks < 4; ++ks)
        acc[mi + 2][0] = MFMA32(a23[mi][ks], bfv[ks], acc[mi + 2][0]);
    __builtin_amdgcn_s_setprio(0);
    __builtin_amdgcn_s_barrier();
    // ---------- phase 3: B(ni1) reads; MFMA mi0-1 x ni1 ----------
#pragma unroll
    for (int ks = 0; ks < 4; ++ks)
      bfv[ks] = *(const bf16x8*)&Bl[(brow + 32 + l31) * 64 + ((ks * 16 + lk8) ^ rswz)];
    if (t + 2 < NT) STG(buf, 0, 0, t + 2);
    __builtin_amdgcn_s_barrier();
    __builtin_amdgcn_s_setprio(1);
#pragma unroll
    for (int mi = 0; mi < 2; ++mi)
#pragma unroll
      for (int ks = 0; ks < 4; ++ks)
        acc[mi][1] = MFMA32(a01[mi][ks], bfv[ks], acc[mi][1]);
    __builtin_amdgcn_s_setprio(0);
    __builtin_amdgcn_s_barrier();
    // ---------- phase 4: MFMA mi2-3 x ni1 ----------
    if (t + 2 < NT) {
      STG(buf, 0, 1, t + 2);
      asm volatile("s_waitcnt vmcnt(4)" ::: "memory");  // all of K-tile t+1 landed
    } else {
      asm volatile("s_waitcnt vmcnt(0)" ::: "memory");
    }
    __builtin_amdgcn_s_barrier();
    __builtin_amdgcn_s_setprio(1);
#pragma unroll
    for (int mi = 0; mi < 2; ++mi)
#pragma unroll
      for (int ks = 0; ks < 4; ++ks)
        acc[mi + 2][1] = MFMA32(a23[mi][ks], bfv[ks], acc[mi + 2][1]);
    __builtin_amdgcn_s_setprio(0);
    __builtin_amdgcn_s_barrier();
  }
#undef STG

  // epilogue: C/D layout col=lane&31, row=(reg&3)+8*(reg>>2)+4*(lane>>5)
#pragma unroll
  for (int ni = 0; ni < 2; ++ni) {
    const int col = bn + wn * 64 + ni * 32 + l31;
    const float bv = bias[col];
#pragma unroll
    for (int mi = 0; mi < 4; ++mi) {
      const int rowbase = bm + wm * 128 + mi * 32 + 4 * (l >> 5);
#pragma unroll
      for (int r = 0; r < 16; ++r) {
        const int row = rowbase + (r & 3) + 8 * (r >> 2);
        float v = acc[mi][ni][r] + bv;
        if (OUT_BF16) ((u16*)Cv)[(size_t)row * N + col] = f2bf(v);
        else          ((float*)Cv)[(size_t)row * N + col] = v;
      }
    }
  }
}

// ---------------- causal flash attention (R8 version, best measured) ----------------
// 4 waves/block, QBLK=64 (wave owns 16 rows), KVBLK=64, K/V double-buffered +
// XOR-swizzled in LDS. Longest-first block remap (qb = 31 - (blk>>6)) kills
// the load-imbalance tail; exp2-domain softmax (log2e in Q), defer-max THR=8,
// causal n-block / PV-half skips.
__global__ __launch_bounds__(256) void attn_k(
    const u16* __restrict__ Q, const u16* __restrict__ K,
    const u16* __restrict__ Vt, u16* __restrict__ O) {
  __shared__ alignas(16) u16 kbuf[2][64 * 128];
  __shared__ alignas(16) u16 vbuf[2][128 * 64];
  __shared__ alignas(16) u16 plds[4][16 * 64];
  const int blk = blockIdx.x;
  const int qb = 31 - (blk >> 6);          // longest blocks dispatch first
  const int bhid = blk & 63;
  const int b = bhid >> 5, h = bhid & 31;
  const int tid = threadIdx.x;
  const int w = tid >> 6, l = tid & 63;
  const int lr = l & 15, lg = l >> 4;
  const size_t bh = (size_t)(b * NH + h);
  const u16* Qp = Q + (bh * S_LEN + (size_t)qb * 64 + (size_t)w * 16) * HD;
  const u16* Kp = K + bh * S_LEN * HD;
  const u16* Vp = Vt + bh * HD * S_LEN;

  bf16x8 qf[4];
#pragma unroll
  for (int kd = 0; kd < 4; ++kd)
    qf[kd] = *(const bf16x8*)&Qp[lr * HD + kd * 32 + lg * 8];

  f32x4 oacc[8] = {};
  float m[4], lsum[4];
#pragma unroll
  for (int r = 0; r < 4; ++r) { m[r] = -1e30f; lsum[r] = 0.f; }
  const int nsteps = qb + 1;
  const int qmin = qb * 64 + w * 16;       // wave-uniform first q row
  const int qrow0 = qmin + lg * 4;

#define ASTAGE(buf, kv0) do { \
    _Pragma("unroll") \
    for (int c = 0; c < 4; ++c) { \
      const int kr = c * 16 + (tid >> 4); \
      const int kc = ((tid & 15) * 8) ^ ((kr & 7) << 3); \
      gload16(Kp + (size_t)((kv0) + kr) * HD + kc, &kbuf[buf][c * 2048 + tid * 8]); \
      const int vr = c * 32 + (tid >> 3); \
      const int vc = ((tid & 7) * 8) ^ ((vr & 7) << 3); \
      gload16(Vp + (size_t)vr * S_LEN + (kv0) + vc, &vbuf[buf][c * 2048 + tid * 8]); \
    } \
  } while (0)

  ASTAGE(0, 0);
  for (int st = 0; st < nsteps; ++st) {
    const int kv0 = st * 64;
    const int cur = st & 1;
    __syncthreads();                       // stage(cur) landed; buf cur^1 free
    if (st + 1 < nsteps) ASTAGE(cur ^ 1, kv0 + 64);

    const int qmaxw = qmin + 15;
    const int na0 = ((qmaxw - kv0) >> 4) + 1;
    const int na = na0 > 4 ? 4 : na0;      // active 16-col n-blocks (wave-uniform)

    // ---- QK^T (active n-blocks only) ----
    f32x4 sacc[4] = {};
#pragma unroll
    for (int n = 0; n < 4; ++n) {
      if (n < na) {
        const int krow = n * 16 + lr;
        const int swzk = (krow & 7) << 3;
#pragma unroll
        for (int kd = 0; kd < 4; ++kd) {
          const bf16x8 kf = *(const bf16x8*)&kbuf[cur][krow * 128 + ((kd * 32 + lg * 8) ^ swzk)];
          sacc[n] = MFMA16(qf[kd], kf, sacc[n]);
        }
      }
    }
    // ---- causal mask (skip when step fully below diagonal) ----
    float sv[4][4];
    if (kv0 + 63 <= qmin) {
#pragma unroll
      for (int n = 0; n < 4; ++n)
#pragma unroll
        for (int r = 0; r < 4; ++r) sv[n][r] = sacc[n][r];
    } else {
#pragma unroll
      for (int n = 0; n < 4; ++n) {
        const int col = kv0 + n * 16 + lr;
#pragma unroll
        for (int r = 0; r < 4; ++r)
          sv[n][r] = (col <= qrow0 + r) ? sacc[n][r] : -1e30f;
      }
    }
    // ---- row max + defer-max (THR=8 in exp2 domain) ----
    float vmx[4];
#pragma unroll
    for (int r = 0; r < 4; ++r) {
      float v = fmaxf(fmaxf(sv[0][r], sv[1][r]), fmaxf(sv[2][r], sv[3][r]));
#pragma unroll
      for (int off = 1; off < 16; off <<= 1)
        v = fmaxf(v, __shfl_xor(v, off, 16));
      vmx[r] = v;
    }
    bool ok = true;
#pragma unroll
    for (int r = 0; r < 4; ++r) ok &= (vmx[r] <= m[r] + 8.f);
    if (!__all(ok)) {
      float al[4];
#pragma unroll
      for (int r = 0; r < 4; ++r) {
        float mn = fmaxf(m[r], vmx[r]);
        al[r] = fexp2(m[r] - mn);
        m[r] = mn;
        lsum[r] *= al[r];
      }
#pragma unroll
      for (int db = 0; db < 8; ++db)
#pragma unroll
        for (int r = 0; r < 4; ++r)
          oacc[db][r] *= al[r];
    }
    // ---- P = 2^(sv-m), write to LDS, row-sum ----
#pragma unroll
    for (int r = 0; r < 4; ++r) {
      const int prow = lg * 4 + r;
      const int pswz = (prow & 7) << 3;
      float ps = 0.f;
#pragma unroll
      for (int n = 0; n < 4; ++n) {
        float p = fexp2(sv[n][r] - m[r]);
        plds[w][prow * 64 + ((n * 16 + lr) ^ pswz)] = f2bf(p);
        ps += p;
      }
#pragma unroll
      for (int off = 1; off < 16; off <<= 1)
        ps += __shfl_xor(ps, off, 16);
      lsum[r] += ps;
    }
    // ---- PV (skip fully-masked 32-col halves) ----
#pragma unroll
    for (int ks = 0; ks < 2; ++ks) {
      if (kv0 + ks * 32 > qmaxw) continue;   // wave-uniform, P==0 there
      const bf16x8 pf = *(const bf16x8*)&plds[w][lr * 64 + ((ks * 32 + lg * 8) ^ ((lr & 7) << 3))];
#pragma unroll
      for (int db = 0; db < 8; ++db) {
        const int vrow = db * 16 + lr;
        const bf16x8 vf = *(const bf16x8*)&vbuf[cur][vrow * 64 + ((ks * 32 + lg * 8) ^ ((vrow & 7) << 3))];
        oacc[db] = MFMA16(pf, vf, oacc[db]);
      }
    }
  }
#undef ASTAGE

  u16* Op = O + ((size_t)b * S_LEN + (size_t)qb * 64 + (size_t)w * 16) * HIDN + h * HD;
#pragma unroll
  for (int db = 0; db < 8; ++db)
#pragma unroll
    for (int r = 0; r < 4; ++r)
      Op[(size_t)(lg * 4 + r) * HIDN + db * 16 + lr] = f2bf(oacc[db][r] / lsum[r]);
}

// ---------------- launcher ----------------
extern "C" void kernel_launch(void* const* d_in, const int* in_sizes, int n_in,
                              void* d_out, int out_size, void* d_ws, size_t ws_size,
                              hipStream_t stream) {
  const int*   positions = (const int*)d_in[0];
  const float* hidden    = (const float*)d_in[1];
  const float* Wqkv      = (const float*)d_in[2];
  const float* bqkv      = (const float*)d_in[3];
  const float* Wo        = (const float*)d_in[4];
  const float* bo        = (const float*)d_in[5];
  float* out = (float*)d_out;
  char* ws = (char*)d_ws;

  // workspace layout (bytes)
  u16*   WqkvT = (u16*)(ws + 0);            // [12288][4096] bf16, 96 MiB
  u16*   WoT   = (u16*)(ws + 100663296);    // [4096][4096] bf16, 32 MiB
  u16*   Xb    = (u16*)(ws + 134217728);    // [4096][4096] bf16, 32 MiB
  float* cosT  = (float*)(ws + 167772160);  // [2048][64] f32
  float* sinT  = (float*)(ws + 168296448);
  u16*   QKV   = (u16*)(ws + 168820736);    // [4096][12288] bf16, 96 MiB
  // aliases: WqkvT dead after GEMM1 -> holds Q,K,Vt ; Xb dead after GEMM1 -> holds O
  u16* Qr  = WqkvT;
  u16* Kr  = WqkvT + 16777216;
  u16* Vtr = WqkvT + 33554432;
  u16* Ob  = Xb;

  transpose_cast<<<dim3(384, 128), dim3(32, 8), 0, stream>>>(Wqkv, WqkvT, 4096, 12288);
  transpose_cast<<<dim3(128, 128), dim3(32, 8), 0, stream>>>(Wo, WoT, 4096, 4096);
  cast_bf16_k<<<16384, 256, 0, stream>>>(hidden, Xb, 4194304);
  rope_table_k<<<512, 256, 0, stream>>>(positions, cosT, sinT);
  gemm256<1><<<768, 512, 0, stream>>>(Xb, WqkvT, bqkv, QKV, 4096, 12288, 4096, 16);
  rope_apply<<<4096, 256, 0, stream>>>(QKV, cosT, sinT, Qr, Kr);
  v_transpose<<<dim3(64, 4, 64), dim3(32, 8), 0, stream>>>(QKV, Vtr);
  attn_k<<<2048, 256, 0, stream>>>(Qr, Kr, Vtr, Ob);
  gemm256<0><<<256, 512, 0, stream>>>(Ob, WoT, bo, out, 4096, 4096, 4096, 16);
}

// Round 12
// 785.374 us; speedup vs baseline: 1.1051x; 1.1051x over previous
//
#include <hip/hip_runtime.h>
#include <hip/hip_bf16.h>

#define S_LEN 2048
#define HIDN  4096
#define NH    32
#define HD    128

typedef __attribute__((ext_vector_type(8))) __bf16 bf16x8;
typedef __attribute__((ext_vector_type(4))) float  f32x4;
typedef unsigned short u16;

__device__ __forceinline__ float bf2f(u16 u) {
  unsigned v = ((unsigned)u) << 16;
  return __builtin_bit_cast(float, v);
}
__device__ __forceinline__ u16 f2bf(float f) {
  unsigned u = __builtin_bit_cast(unsigned, f);
  u += 0x7FFFu + ((u >> 16) & 1u);
  return (u16)(u >> 16);
}
__device__ __forceinline__ float fexp2(float x) {   // 2^x, single v_exp_f32
  float r; asm("v_exp_f32 %0, %1" : "=v"(r) : "v"(x)); return r;
}
__device__ __forceinline__ void gload16(const void* g, void* l) {
  __builtin_amdgcn_global_load_lds((const __attribute__((address_space(1))) void*)g,
                                   (__attribute__((address_space(3))) void*)l, 16, 0, 0);
}
#define MFMA16(a, b, c) __builtin_amdgcn_mfma_f32_16x16x32_bf16(a, b, c, 0, 0, 0)

// ---------------- prep kernels ----------------

// f32 [R][C] -> bf16 [C][R]
__global__ void transpose_cast(const float* __restrict__ in, u16* __restrict__ out,
                               int R, int C) {
  __shared__ float t[32][33];
  const int c0 = blockIdx.x * 32, r0 = blockIdx.y * 32;
  const int tx = threadIdx.x, ty = threadIdx.y;
#pragma unroll
  for (int i = 0; i < 4; ++i)
    t[ty + i * 8][tx] = in[(size_t)(r0 + ty + i * 8) * C + c0 + tx];
  __syncthreads();
#pragma unroll
  for (int i = 0; i < 4; ++i)
    out[(size_t)(c0 + ty + i * 8) * R + r0 + tx] = f2bf(t[tx][ty + i * 8]);
}

struct u16x4s { u16 x, y, z, w; };

__global__ void cast_bf16_k(const float* __restrict__ in, u16* __restrict__ out, int n4) {
  int i = blockIdx.x * 256 + threadIdx.x;
  if (i < n4) {
    float4 v = ((const float4*)in)[i];
    u16x4s o;
    o.x = f2bf(v.x); o.y = f2bf(v.y); o.z = f2bf(v.z); o.w = f2bf(v.w);
    ((u16x4s*)out)[i] = o;
  }
}

__global__ void rope_table_k(const int* __restrict__ pos, float* __restrict__ cs,
                             float* __restrict__ sn) {
  int idx = blockIdx.x * 256 + threadIdx.x;   // S_LEN*64 total
  int s = idx >> 6, d = idx & 63;
  float inv = exp2f((-(float)d / 64.f) * 13.287712379549449f); // log2(10000)
  float ang = (float)pos[s] * inv;
  cs[idx] = cosf(ang);
  sn[idx] = sinf(ang);
}

// ---------------- 256x256 4-phase GEMM (16x16x32, R10-proven K-loop) ----------------
// C[M][N] = A[M][K] * Bt[N][K]^T + bias. 512 threads = 8 waves (2M x 4N),
// per-wave output 128x64. BK=64; LDS = 2buf x {A,B} x {2 halves} = 128 KiB,
// XOR-slot swizzled (0 bank conflicts). bm-fastest swizzle for B L2 reuse.
// EPI=0: plain f32 output (O-projection).
// EPI=1: fused QKV epilogue — dump acc+bias to the (now dead) 128KB LDS as a
//        256x256 tile, then per bn-region: Q/K -> rope'd [B,H,S,D] bf16
//        (pairs (d,d+64) same-thread via LDS), V -> transposed [B,H,D,S].
//        K-loop sync structure untouched; dump is safe because all LDS reads
//        complete before the loop's final barrier.
template <int EPI>
__global__ __launch_bounds__(512) void gemm256(
    const u16* __restrict__ A, const u16* __restrict__ Bt,
    const float* __restrict__ bias, void* __restrict__ Cv,
    int M, int N, int K, int nbm,
    u16* __restrict__ Qo, u16* __restrict__ Ko, u16* __restrict__ Vo,
    const float* __restrict__ cs, const float* __restrict__ sn) {
  __shared__ alignas(16) u16 lds[2][2][2][128 * 64];
  const int tid = threadIdx.x;
  const int cpx = gridDim.x >> 3;
  const int swz = (blockIdx.x & 7) * cpx + (blockIdx.x >> 3);   // bijective (nb%8==0)
  const int bm = (swz % nbm) * 256, bn = (swz / nbm) * 256;     // bm fastest: B reuse in L2
  const int w = tid >> 6, l = tid & 63;
  const int wm = w >> 2, wn = w & 3;
  const int lr = l & 15, lg = l >> 4;
  const int rswz = (lr & 7) * 8;                  // read-side XOR (u16 units)
  const int rl = tid >> 3;                        // staging row (per 8 threads)
  const int sl = (tid & 7) ^ ((tid >> 3) & 7);    // staging source slot (inverse swz)
  const u16* Ap = A + (size_t)bm * K;
  const u16* Bp = Bt + (size_t)bn * K;

#define STG(buf, ab, half, kt) do { \
    const u16* s_ = (ab ? Bp : Ap) + (size_t)((half) * 128 + rl) * K + (kt) * 64 + sl * 8; \
    u16* d_ = &lds[buf][ab][half][tid * 8]; \
    gload16(s_, d_); \
    gload16(s_ + (size_t)64 * K, d_ + 4096); \
  } while (0)

  f32x4 acc[8][4] = {};
  // prologue: K-tile 0 complete + K-tile 1 A halves = 12 loads
  STG(0, 0, 0, 0); STG(0, 0, 1, 0); STG(0, 1, 0, 0); STG(0, 1, 1, 0);
  STG(1, 0, 0, 1); STG(1, 0, 1, 1);
  asm volatile("s_waitcnt vmcnt(4)" ::: "memory");   // K-tile 0 landed
  __builtin_amdgcn_s_barrier();

  const int NT = K >> 6;
  bf16x8 alo[4][2], ahi[4][2], bfr[2][2];
  for (int t = 0; t < NT; ++t) {
    const int buf = t & 1;
    const u16* Al = &lds[buf][0][wm][0];
    const u16* Bl = &lds[buf][1][wn >> 1][0];
    const int brow = (wn & 1) * 64;
    // ---------- phase 1 ----------
#pragma unroll
    for (int mi = 0; mi < 4; ++mi)
#pragma unroll
      for (int ks = 0; ks < 2; ++ks)
        alo[mi][ks] = *(const bf16x8*)&Al[(mi * 16 + lr) * 64 + ((ks * 32 + lg * 8) ^ rswz)];
#pragma unroll
    for (int ni = 0; ni < 2; ++ni)
#pragma unroll
      for (int ks = 0; ks < 2; ++ks)
        bfr[ni][ks] = *(const bf16x8*)&Bl[(brow + ni * 16 + lr) * 64 + ((ks * 32 + lg * 8) ^ rswz)];
    if (t + 1 < NT) STG(buf ^ 1, 1, 0, t + 1);
    __builtin_amdgcn_s_barrier();
    __builtin_amdgcn_s_setprio(1);
#pragma unroll
    for (int mi = 0; mi < 4; ++mi)
#pragma unroll
      for (int ni = 0; ni < 2; ++ni)
#pragma unroll
        for (int ks = 0; ks < 2; ++ks)
          acc[mi][ni] = MFMA16(alo[mi][ks], bfr[ni][ks], acc[mi][ni]);
    __builtin_amdgcn_s_setprio(0);
    __builtin_amdgcn_s_barrier();
    // ---------- phase 2 ----------
#pragma unroll
    for (int mi = 0; mi < 4; ++mi)
#pragma unroll
      for (int ks = 0; ks < 2; ++ks)
        ahi[mi][ks] = *(const bf16x8*)&Al[((mi + 4) * 16 + lr) * 64 + ((ks * 32 + lg * 8) ^ rswz)];
    if (t + 1 < NT) STG(buf ^ 1, 1, 1, t + 1);
    __builtin_amdgcn_s_barrier();
    __builtin_amdgcn_s_setprio(1);
#pragma unroll
    for (int mi = 0; mi < 4; ++mi)
#pragma unroll
      for (int ni = 0; ni < 2; ++ni)
#pragma unroll
        for (int ks = 0; ks < 2; ++ks)
          acc[mi + 4][ni] = MFMA16(ahi[mi][ks], bfr[ni][ks], acc[mi + 4][ni]);
    __builtin_amdgcn_s_setprio(0);
    __builtin_amdgcn_s_barrier();
    // ---------- phase 3 ----------
#pragma unroll
    for (int ni = 0; ni < 2; ++ni)
#pragma unroll
      for (int ks = 0; ks < 2; ++ks)
        bfr[ni][ks] = *(const bf16x8*)&Bl[(brow + (ni + 2) * 16 + lr) * 64 + ((ks * 32 + lg * 8) ^ rswz)];
    if (t + 2 < NT) STG(buf, 0, 0, t + 2);
    __builtin_amdgcn_s_barrier();
    __builtin_amdgcn_s_setprio(1);
#pragma unroll
    for (int mi = 0; mi < 4; ++mi)
#pragma unroll
      for (int ni = 0; ni < 2; ++ni)
#pragma unroll
        for (int ks = 0; ks < 2; ++ks)
          acc[mi][ni + 2] = MFMA16(alo[mi][ks], bfr[ni][ks], acc[mi][ni + 2]);
    __builtin_amdgcn_s_setprio(0);
    __builtin_amdgcn_s_barrier();
    // ---------- phase 4 ----------
    if (t + 2 < NT) {
      STG(buf, 0, 1, t + 2);
      asm volatile("s_waitcnt vmcnt(4)" ::: "memory");  // all of K-tile t+1 landed
    } else {
      asm volatile("s_waitcnt vmcnt(0)" ::: "memory");
    }
    __builtin_amdgcn_s_barrier();
    __builtin_amdgcn_s_setprio(1);
#pragma unroll
    for (int mi = 0; mi < 4; ++mi)
#pragma unroll
      for (int ni = 0; ni < 2; ++ni)
#pragma unroll
        for (int ks = 0; ks < 2; ++ks)
          acc[mi + 4][ni + 2] = MFMA16(ahi[mi][ks], bfr[ni][ks], acc[mi + 4][ni + 2]);
    __builtin_amdgcn_s_setprio(0);
    __builtin_amdgcn_s_barrier();
  }
#undef STG

  if (EPI == 0) {
#pragma unroll
    for (int ni = 0; ni < 4; ++ni) {
      const int col = bn + wn * 64 + ni * 16 + lr;
      const float bv = bias[col];
#pragma unroll
      for (int mi = 0; mi < 8; ++mi) {
        const int row = bm + wm * 128 + mi * 16 + lg * 4;
#pragma unroll
        for (int r = 0; r < 4; ++r)
          ((float*)Cv)[(size_t)(row + r) * N + col] = acc[mi][ni][r] + bv;
      }
    }
  } else {
    // ---- fused QKV epilogue ----
    u16* tile = (u16*)lds;          // 256x256 bf16 = 128 KiB (K-loop buffers dead)
    const int cr = lg * 4, cc = lr;
#pragma unroll
    for (int ni = 0; ni < 4; ++ni) {
      const int lcol = wn * 64 + ni * 16 + cc;
      const float bv = bias[bn + lcol];
#pragma unroll
      for (int mi = 0; mi < 8; ++mi) {
        const int lrow = wm * 128 + mi * 16 + cr;
#pragma unroll
        for (int r = 0; r < 4; ++r)
          tile[(lrow + r) * 256 + lcol] = f2bf(acc[mi][ni][r] + bv);
      }
    }
    __syncthreads();
    if (bn < 2 * HIDN) {
      // Q or K tile: rope pairs (d, d+64) now same-thread via LDS
      const float sc = (bn < HIDN) ? 0.12751743f : 1.0f;  // (1/sqrt(128))*log2e in Q
      u16* dst0 = (bn < HIDN) ? Qo : Ko;
      const int hbase = (bn & (HIDN - 1)) >> 7;
#pragma unroll
      for (int it = 0; it < 8; ++it) {
        const int idx = it * 512 + tid;                   // 2 heads*256 s*8 chunks
        const int hh = idx >> 11, slc = (idx >> 3) & 255, d0 = (idx & 7) * 8;
        const bf16x8 va = *(const bf16x8*)&tile[slc * 256 + hh * 128 + d0];
        const bf16x8 vb = *(const bf16x8*)&tile[slc * 256 + hh * 128 + 64 + d0];
        const int sg = bm + slc, b_ = sg >> 11, s_ = sg & 2047;
        const float4 c0 = *(const float4*)&cs[s_ * 64 + d0];
        const float4 c1 = *(const float4*)&cs[s_ * 64 + d0 + 4];
        const float4 s0v = *(const float4*)&sn[s_ * 64 + d0];
        const float4 s1v = *(const float4*)&sn[s_ * 64 + d0 + 4];
        bf16x8 r1, r2;
#pragma unroll
        for (int j = 0; j < 8; ++j) {
          float x1 = (float)va[j], x2 = (float)vb[j];
          float cj = (j < 4) ? c0[j & 3] : c1[j & 3];
          float sj = (j < 4) ? s0v[j & 3] : s1v[j & 3];
          r1[j] = (__bf16)((x1 * cj - x2 * sj) * sc);
          r2[j] = (__bf16)((x2 * cj + x1 * sj) * sc);
        }
        u16* dp = dst0 + ((size_t)(b_ * NH + hbase + hh) * S_LEN + s_) * HD + d0;
        *(bf16x8*)dp = r1;
        *(bf16x8*)(dp + 64) = r2;
      }
    } else {
      // V tile: transpose to Vt[B,H,D,S]
      const int hbase = (bn - 2 * HIDN) >> 7;
#pragma unroll
      for (int it = 0; it < 16; ++it) {
        const int idx = it * 512 + tid;                   // 32 s-chunks * 256 cols
        const int sc8 = idx >> 8, cl = idx & 255;
        const int s0 = sc8 * 8;
        bf16x8 v;
#pragma unroll
        for (int j = 0; j < 8; ++j)
          v[j] = __builtin_bit_cast(__bf16, tile[(s0 + j) * 256 + cl]);
        const int sg = bm + s0, b_ = sg >> 11, s_ = sg & 2047;
        const int h_ = hbase + (cl >> 7), d_ = cl & 127;
        *(bf16x8*)&Vo[((size_t)(b_ * NH + h_) * HD + d_) * S_LEN + s_] = v;
      }
    }
  }
}

// ---------------- causal flash attention (R8/R10 version, best measured) ------------
// 4 waves/block, QBLK=64 (wave owns 16 rows), KVBLK=64, K/V double-buffered +
// XOR-swizzled in LDS. Longest-first block remap (qb = 31 - (blk>>6)) kills
// the load-imbalance tail; exp2-domain softmax (log2e in Q), defer-max THR=8,
// causal n-block / PV-half skips.
__global__ __launch_bounds__(256) void attn_k(
    const u16* __restrict__ Q, const u16* __restrict__ K,
    const u16* __restrict__ Vt, u16* __restrict__ O) {
  __shared__ alignas(16) u16 kbuf[2][64 * 128];
  __shared__ alignas(16) u16 vbuf[2][128 * 64];
  __shared__ alignas(16) u16 plds[4][16 * 64];
  const int blk = blockIdx.x;
  const int qb = 31 - (blk >> 6);          // longest blocks dispatch first
  const int bhid = blk & 63;
  const int b = bhid >> 5, h = bhid & 31;
  const int tid = threadIdx.x;
  const int w = tid >> 6, l = tid & 63;
  const int lr = l & 15, lg = l >> 4;
  const size_t bh = (size_t)(b * NH + h);
  const u16* Qp = Q + (bh * S_LEN + (size_t)qb * 64 + (size_t)w * 16) * HD;
  const u16* Kp = K + bh * S_LEN * HD;
  const u16* Vp = Vt + bh * HD * S_LEN;

  bf16x8 qf[4];
#pragma unroll
  for (int kd = 0; kd < 4; ++kd)
    qf[kd] = *(const bf16x8*)&Qp[lr * HD + kd * 32 + lg * 8];

  f32x4 oacc[8] = {};
  float m[4], lsum[4];
#pragma unroll
  for (int r = 0; r < 4; ++r) { m[r] = -1e30f; lsum[r] = 0.f; }
  const int nsteps = qb + 1;
  const int qmin = qb * 64 + w * 16;       // wave-uniform first q row
  const int qrow0 = qmin + lg * 4;

#define ASTAGE(buf, kv0) do { \
    _Pragma("unroll") \
    for (int c = 0; c < 4; ++c) { \
      const int kr = c * 16 + (tid >> 4); \
      const int kc = ((tid & 15) * 8) ^ ((kr & 7) << 3); \
      gload16(Kp + (size_t)((kv0) + kr) * HD + kc, &kbuf[buf][c * 2048 + tid * 8]); \
      const int vr = c * 32 + (tid >> 3); \
      const int vc = ((tid & 7) * 8) ^ ((vr & 7) << 3); \
      gload16(Vp + (size_t)vr * S_LEN + (kv0) + vc, &vbuf[buf][c * 2048 + tid * 8]); \
    } \
  } while (0)

  ASTAGE(0, 0);
  for (int st = 0; st < nsteps; ++st) {
    const int kv0 = st * 64;
    const int cur = st & 1;
    __syncthreads();                       // stage(cur) landed; buf cur^1 free
    if (st + 1 < nsteps) ASTAGE(cur ^ 1, kv0 + 64);

    const int qmaxw = qmin + 15;
    const int na0 = ((qmaxw - kv0) >> 4) + 1;
    const int na = na0 > 4 ? 4 : na0;      // active 16-col n-blocks (wave-uniform)

    // ---- QK^T (active n-blocks only) ----
    f32x4 sacc[4] = {};
#pragma unroll
    for (int n = 0; n < 4; ++n) {
      if (n < na) {
        const int krow = n * 16 + lr;
        const int swzk = (krow & 7) << 3;
#pragma unroll
        for (int kd = 0; kd < 4; ++kd) {
          const bf16x8 kf = *(const bf16x8*)&kbuf[cur][krow * 128 + ((kd * 32 + lg * 8) ^ swzk)];
          sacc[n] = MFMA16(qf[kd], kf, sacc[n]);
        }
      }
    }
    // ---- causal mask (skip when step fully below diagonal) ----
    float sv[4][4];
    if (kv0 + 63 <= qmin) {
#pragma unroll
      for (int n = 0; n < 4; ++n)
#pragma unroll
        for (int r = 0; r < 4; ++r) sv[n][r] = sacc[n][r];
    } else {
#pragma unroll
      for (int n = 0; n < 4; ++n) {
        const int col = kv0 + n * 16 + lr;
#pragma unroll
        for (int r = 0; r < 4; ++r)
          sv[n][r] = (col <= qrow0 + r) ? sacc[n][r] : -1e30f;
      }
    }
    // ---- row max + defer-max (THR=8 in exp2 domain) ----
    float vmx[4];
#pragma unroll
    for (int r = 0; r < 4; ++r) {
      float v = fmaxf(fmaxf(sv[0][r], sv[1][r]), fmaxf(sv[2][r], sv[3][r]));
#pragma unroll
      for (int off = 1; off < 16; off <<= 1)
        v = fmaxf(v, __shfl_xor(v, off, 16));
      vmx[r] = v;
    }
    bool ok = true;
#pragma unroll
    for (int r = 0; r < 4; ++r) ok &= (vmx[r] <= m[r] + 8.f);
    if (!__all(ok)) {
      float al[4];
#pragma unroll
      for (int r = 0; r < 4; ++r) {
        float mn = fmaxf(m[r], vmx[r]);
        al[r] = fexp2(m[r] - mn);
        m[r] = mn;
        lsum[r] *= al[r];
      }
#pragma unroll
      for (int db = 0; db < 8; ++db)
#pragma unroll
        for (int r = 0; r < 4; ++r)
          oacc[db][r] *= al[r];
    }
    // ---- P = 2^(sv-m), write to LDS, row-sum ----
#pragma unroll
    for (int r = 0; r < 4; ++r) {
      const int prow = lg * 4 + r;
      const int pswz = (prow & 7) << 3;
      float ps = 0.f;
#pragma unroll
      for (int n = 0; n < 4; ++n) {
        float p = fexp2(sv[n][r] - m[r]);
        plds[w][prow * 64 + ((n * 16 + lr) ^ pswz)] = f2bf(p);
        ps += p;
      }
#pragma unroll
      for (int off = 1; off < 16; off <<= 1)
        ps += __shfl_xor(ps, off, 16);
      lsum[r] += ps;
    }
    // ---- PV (skip fully-masked 32-col halves) ----
#pragma unroll
    for (int ks = 0; ks < 2; ++ks) {
      if (kv0 + ks * 32 > qmaxw) continue;   // wave-uniform, P==0 there
      const bf16x8 pf = *(const bf16x8*)&plds[w][lr * 64 + ((ks * 32 + lg * 8) ^ ((lr & 7) << 3))];
#pragma unroll
      for (int db = 0; db < 8; ++db) {
        const int vrow = db * 16 + lr;
        const bf16x8 vf = *(const bf16x8*)&vbuf[cur][vrow * 64 + ((ks * 32 + lg * 8) ^ ((vrow & 7) << 3))];
        oacc[db] = MFMA16(pf, vf, oacc[db]);
      }
    }
  }
#undef ASTAGE

  u16* Op = O + ((size_t)b * S_LEN + (size_t)qb * 64 + (size_t)w * 16) * HIDN + h * HD;
#pragma unroll
  for (int db = 0; db < 8; ++db)
#pragma unroll
    for (int r = 0; r < 4; ++r)
      Op[(size_t)(lg * 4 + r) * HIDN + db * 16 + lr] = f2bf(oacc[db][r] / lsum[r]);
}

// ---------------- launcher ----------------
extern "C" void kernel_launch(void* const* d_in, const int* in_sizes, int n_in,
                              void* d_out, int out_size, void* d_ws, size_t ws_size,
                              hipStream_t stream) {
  const int*   positions = (const int*)d_in[0];
  const float* hidden    = (const float*)d_in[1];
  const float* Wqkv      = (const float*)d_in[2];
  const float* bqkv      = (const float*)d_in[3];
  const float* Wo        = (const float*)d_in[4];
  const float* bo        = (const float*)d_in[5];
  float* out = (float*)d_out;
  char* ws = (char*)d_ws;

  // workspace layout (bytes)
  u16*   WqkvT = (u16*)(ws + 0);            // [12288][4096] bf16, 96 MiB
  u16*   WoT   = (u16*)(ws + 100663296);    // [4096][4096] bf16, 32 MiB
  u16*   Xb    = (u16*)(ws + 134217728);    // [4096][4096] bf16, 32 MiB
  float* cosT  = (float*)(ws + 167772160);  // [2048][64] f32
  float* sinT  = (float*)(ws + 168296448);
  // Q/K/Vt written directly by GEMM1's fused epilogue (NOT aliased onto WqkvT —
  // GEMM1 reads WqkvT while writing these)
  u16* Qr  = (u16*)(ws + 168820736);        // 32 MiB
  u16* Kr  = Qr + 16777216;                 // 32 MiB
  u16* Vtr = Kr + 16777216;                 // 32 MiB
  u16* Ob  = Xb;                            // Xb dead after GEMM1

  transpose_cast<<<dim3(384, 128), dim3(32, 8), 0, stream>>>(Wqkv, WqkvT, 4096, 12288);
  transpose_cast<<<dim3(128, 128), dim3(32, 8), 0, stream>>>(Wo, WoT, 4096, 4096);
  cast_bf16_k<<<16384, 256, 0, stream>>>(hidden, Xb, 4194304);
  rope_table_k<<<512, 256, 0, stream>>>(positions, cosT, sinT);
  gemm256<1><<<768, 512, 0, stream>>>(Xb, WqkvT, bqkv, nullptr, 4096, 12288, 4096, 16,
                                      Qr, Kr, Vtr, cosT, sinT);
  attn_k<<<2048, 256, 0, stream>>>(Qr, Kr, Vtr, Ob);
  gemm256<0><<<256, 512, 0, stream>>>(Ob, WoT, bo, out, 4096, 4096, 4096, 16,
                                      nullptr, nullptr, nullptr, nullptr, nullptr);
}

// Round 13
// 734.840 us; speedup vs baseline: 1.1811x; 1.0688x over previous
//
#include <hip/hip_runtime.h>
#include <hip/hip_bf16.h>

#define S_LEN 2048
#define HIDN  4096
#define NH    32
#define HD    128

typedef __attribute__((ext_vector_type(8))) __bf16 bf16x8;
typedef __attribute__((ext_vector_type(4))) float  f32x4;
typedef unsigned short u16;

__device__ __forceinline__ float bf2f(u16 u) {
  unsigned v = ((unsigned)u) << 16;
  return __builtin_bit_cast(float, v);
}
__device__ __forceinline__ u16 f2bf(float f) {
  unsigned u = __builtin_bit_cast(unsigned, f);
  u += 0x7FFFu + ((u >> 16) & 1u);
  return (u16)(u >> 16);
}
__device__ __forceinline__ float fexp2(float x) {   // 2^x, single v_exp_f32
  float r; asm("v_exp_f32 %0, %1" : "=v"(r) : "v"(x)); return r;
}
__device__ __forceinline__ void gload16(const void* g, void* l) {
  __builtin_amdgcn_global_load_lds((const __attribute__((address_space(1))) void*)g,
                                   (__attribute__((address_space(3))) void*)l, 16, 0, 0);
}
#define MFMA16(a, b, c) __builtin_amdgcn_mfma_f32_16x16x32_bf16(a, b, c, 0, 0, 0)

// ---------------- prep kernels ----------------

// f32 [R][C] -> bf16 [C][R]
__global__ void transpose_cast(const float* __restrict__ in, u16* __restrict__ out,
                               int R, int C) {
  __shared__ float t[32][33];
  const int c0 = blockIdx.x * 32, r0 = blockIdx.y * 32;
  const int tx = threadIdx.x, ty = threadIdx.y;
#pragma unroll
  for (int i = 0; i < 4; ++i)
    t[ty + i * 8][tx] = in[(size_t)(r0 + ty + i * 8) * C + c0 + tx];
  __syncthreads();
#pragma unroll
  for (int i = 0; i < 4; ++i)
    out[(size_t)(c0 + ty + i * 8) * R + r0 + tx] = f2bf(t[tx][ty + i * 8]);
}

struct u16x4s { u16 x, y, z, w; };

__global__ void cast_bf16_k(const float* __restrict__ in, u16* __restrict__ out, int n4) {
  int i = blockIdx.x * 256 + threadIdx.x;
  if (i < n4) {
    float4 v = ((const float4*)in)[i];
    u16x4s o;
    o.x = f2bf(v.x); o.y = f2bf(v.y); o.z = f2bf(v.z); o.w = f2bf(v.w);
    ((u16x4s*)out)[i] = o;
  }
}

__global__ void rope_table_k(const int* __restrict__ pos, float* __restrict__ cs,
                             float* __restrict__ sn) {
  int idx = blockIdx.x * 256 + threadIdx.x;   // S_LEN*64 total
  int s = idx >> 6, d = idx & 63;
  float inv = exp2f((-(float)d / 64.f) * 13.287712379549449f); // log2(10000)
  float ang = (float)pos[s] * inv;
  cs[idx] = cosf(ang);
  sn[idx] = sinf(ang);
}

// ---------------- 256x256 4-phase GEMM (16x16x32, R10-proven K-loop) ----------------
// EPI=0: plain f32 output (O-projection).
// EPI=1: fused QKV epilogue via LDS tile. Tile is slot-swizzled:
//   logical (row,col) -> lds[row*256 + (((col>>3) ^ (row&7))<<3) + (col&7)]
//   (dump was 4-way bank-conflicted unswizzled: lg groups differ by row*512B =
//    bank-period; XOR of row&7 into the 16B slot spreads them -> 2-way, free.)
template <int EPI>
__global__ __launch_bounds__(512) void gemm256(
    const u16* __restrict__ A, const u16* __restrict__ Bt,
    const float* __restrict__ bias, void* __restrict__ Cv,
    int M, int N, int K, int nbm,
    u16* __restrict__ Qo, u16* __restrict__ Ko, u16* __restrict__ Vo,
    const float* __restrict__ cs, const float* __restrict__ sn) {
  __shared__ alignas(16) u16 lds[2][2][2][128 * 64];
  const int tid = threadIdx.x;
  const int cpx = gridDim.x >> 3;
  const int swz = (blockIdx.x & 7) * cpx + (blockIdx.x >> 3);   // bijective (nb%8==0)
  const int bm = (swz % nbm) * 256, bn = (swz / nbm) * 256;     // bm fastest: B reuse in L2
  const int w = tid >> 6, l = tid & 63;
  const int wm = w >> 2, wn = w & 3;
  const int lr = l & 15, lg = l >> 4;
  const int rswz = (lr & 7) * 8;                  // read-side XOR (u16 units)
  const int rl = tid >> 3;                        // staging row (per 8 threads)
  const int sl = (tid & 7) ^ ((tid >> 3) & 7);    // staging source slot (inverse swz)
  const u16* Ap = A + (size_t)bm * K;
  const u16* Bp = Bt + (size_t)bn * K;

#define STG(buf, ab, half, kt) do { \
    const u16* s_ = (ab ? Bp : Ap) + (size_t)((half) * 128 + rl) * K + (kt) * 64 + sl * 8; \
    u16* d_ = &lds[buf][ab][half][tid * 8]; \
    gload16(s_, d_); \
    gload16(s_ + (size_t)64 * K, d_ + 4096); \
  } while (0)

  f32x4 acc[8][4] = {};
  // prologue: K-tile 0 complete + K-tile 1 A halves = 12 loads
  STG(0, 0, 0, 0); STG(0, 0, 1, 0); STG(0, 1, 0, 0); STG(0, 1, 1, 0);
  STG(1, 0, 0, 1); STG(1, 0, 1, 1);
  asm volatile("s_waitcnt vmcnt(4)" ::: "memory");   // K-tile 0 landed
  __builtin_amdgcn_s_barrier();

  const int NT = K >> 6;
  bf16x8 alo[4][2], ahi[4][2], bfr[2][2];
  for (int t = 0; t < NT; ++t) {
    const int buf = t & 1;
    const u16* Al = &lds[buf][0][wm][0];
    const u16* Bl = &lds[buf][1][wn >> 1][0];
    const int brow = (wn & 1) * 64;
    // ---------- phase 1 ----------
#pragma unroll
    for (int mi = 0; mi < 4; ++mi)
#pragma unroll
      for (int ks = 0; ks < 2; ++ks)
        alo[mi][ks] = *(const bf16x8*)&Al[(mi * 16 + lr) * 64 + ((ks * 32 + lg * 8) ^ rswz)];
#pragma unroll
    for (int ni = 0; ni < 2; ++ni)
#pragma unroll
      for (int ks = 0; ks < 2; ++ks)
        bfr[ni][ks] = *(const bf16x8*)&Bl[(brow + ni * 16 + lr) * 64 + ((ks * 32 + lg * 8) ^ rswz)];
    if (t + 1 < NT) STG(buf ^ 1, 1, 0, t + 1);
    __builtin_amdgcn_s_barrier();
    __builtin_amdgcn_s_setprio(1);
#pragma unroll
    for (int mi = 0; mi < 4; ++mi)
#pragma unroll
      for (int ni = 0; ni < 2; ++ni)
#pragma unroll
        for (int ks = 0; ks < 2; ++ks)
          acc[mi][ni] = MFMA16(alo[mi][ks], bfr[ni][ks], acc[mi][ni]);
    __builtin_amdgcn_s_setprio(0);
    __builtin_amdgcn_s_barrier();
    // ---------- phase 2 ----------
#pragma unroll
    for (int mi = 0; mi < 4; ++mi)
#pragma unroll
      for (int ks = 0; ks < 2; ++ks)
        ahi[mi][ks] = *(const bf16x8*)&Al[((mi + 4) * 16 + lr) * 64 + ((ks * 32 + lg * 8) ^ rswz)];
    if (t + 1 < NT) STG(buf ^ 1, 1, 1, t + 1);
    __builtin_amdgcn_s_barrier();
    __builtin_amdgcn_s_setprio(1);
#pragma unroll
    for (int mi = 0; mi < 4; ++mi)
#pragma unroll
      for (int ni = 0; ni < 2; ++ni)
#pragma unroll
        for (int ks = 0; ks < 2; ++ks)
          acc[mi + 4][ni] = MFMA16(ahi[mi][ks], bfr[ni][ks], acc[mi + 4][ni]);
    __builtin_amdgcn_s_setprio(0);
    __builtin_amdgcn_s_barrier();
    // ---------- phase 3 ----------
#pragma unroll
    for (int ni = 0; ni < 2; ++ni)
#pragma unroll
      for (int ks = 0; ks < 2; ++ks)
        bfr[ni][ks] = *(const bf16x8*)&Bl[(brow + (ni + 2) * 16 + lr) * 64 + ((ks * 32 + lg * 8) ^ rswz)];
    if (t + 2 < NT) STG(buf, 0, 0, t + 2);
    __builtin_amdgcn_s_barrier();
    __builtin_amdgcn_s_setprio(1);
#pragma unroll
    for (int mi = 0; mi < 4; ++mi)
#pragma unroll
      for (int ni = 0; ni < 2; ++ni)
#pragma unroll
        for (int ks = 0; ks < 2; ++ks)
          acc[mi][ni + 2] = MFMA16(alo[mi][ks], bfr[ni][ks], acc[mi][ni + 2]);
    __builtin_amdgcn_s_setprio(0);
    __builtin_amdgcn_s_barrier();
    // ---------- phase 4 ----------
    if (t + 2 < NT) {
      STG(buf, 0, 1, t + 2);
      asm volatile("s_waitcnt vmcnt(4)" ::: "memory");  // all of K-tile t+1 landed
    } else {
      asm volatile("s_waitcnt vmcnt(0)" ::: "memory");
    }
    __builtin_amdgcn_s_barrier();
    __builtin_amdgcn_s_setprio(1);
#pragma unroll
    for (int mi = 0; mi < 4; ++mi)
#pragma unroll
      for (int ni = 0; ni < 2; ++ni)
#pragma unroll
        for (int ks = 0; ks < 2; ++ks)
          acc[mi + 4][ni + 2] = MFMA16(ahi[mi][ks], bfr[ni][ks], acc[mi + 4][ni + 2]);
    __builtin_amdgcn_s_setprio(0);
    __builtin_amdgcn_s_barrier();
  }
#undef STG

  if (EPI == 0) {
#pragma unroll
    for (int ni = 0; ni < 4; ++ni) {
      const int col = bn + wn * 64 + ni * 16 + lr;
      const float bv = bias[col];
#pragma unroll
      for (int mi = 0; mi < 8; ++mi) {
        const int row = bm + wm * 128 + mi * 16 + lg * 4;
#pragma unroll
        for (int r = 0; r < 4; ++r)
          ((float*)Cv)[(size_t)(row + r) * N + col] = acc[mi][ni][r] + bv;
      }
    }
  } else {
    // ---- fused QKV epilogue (slot-swizzled tile) ----
    u16* tile = (u16*)lds;          // 256x256 bf16 = 128 KiB (K-loop buffers dead)
    const int cr = lg * 4, cc = lr;
#pragma unroll
    for (int ni = 0; ni < 4; ++ni) {
      const int lcol = wn * 64 + ni * 16 + cc;
      const float bv = bias[bn + lcol];
#pragma unroll
      for (int mi = 0; mi < 8; ++mi) {
        const int lrow = wm * 128 + mi * 16 + cr;
#pragma unroll
        for (int r = 0; r < 4; ++r) {
          const int rw = lrow + r;
          tile[rw * 256 + ((((lcol >> 3) ^ (rw & 7)) << 3) | (lcol & 7))] =
              f2bf(acc[mi][ni][r] + bv);
        }
      }
    }
    __syncthreads();
    if (bn < 2 * HIDN) {
      // Q or K tile: rope pairs (d, d+64) same-thread via LDS
      const float sc = (bn < HIDN) ? 0.12751743f : 1.0f;  // (1/sqrt(128))*log2e in Q
      u16* dst0 = (bn < HIDN) ? Qo : Ko;
      const int hbase = (bn & (HIDN - 1)) >> 7;
#pragma unroll
      for (int it = 0; it < 8; ++it) {
        const int idx = it * 512 + tid;                   // 2 heads*256 s*8 chunks
        const int hh = idx >> 11, slc = (idx >> 3) & 255, d0 = (idx & 7) * 8;
        const int colA = hh * 128 + d0, colB = colA + 64;
        const bf16x8 va = *(const bf16x8*)&tile[slc * 256 + (((colA >> 3) ^ (slc & 7)) << 3)];
        const bf16x8 vb = *(const bf16x8*)&tile[slc * 256 + (((colB >> 3) ^ (slc & 7)) << 3)];
        const int sg = bm + slc, b_ = sg >> 11, s_ = sg & 2047;
        const float4 c0 = *(const float4*)&cs[s_ * 64 + d0];
        const float4 c1 = *(const float4*)&cs[s_ * 64 + d0 + 4];
        const float4 s0v = *(const float4*)&sn[s_ * 64 + d0];
        const float4 s1v = *(const float4*)&sn[s_ * 64 + d0 + 4];
        bf16x8 r1, r2;
#pragma unroll
        for (int j = 0; j < 8; ++j) {
          float x1 = (float)va[j], x2 = (float)vb[j];
          float cj = (j < 4) ? c0[j & 3] : c1[j & 3];
          float sj = (j < 4) ? s0v[j & 3] : s1v[j & 3];
          r1[j] = (__bf16)((x1 * cj - x2 * sj) * sc);
          r2[j] = (__bf16)((x2 * cj + x1 * sj) * sc);
        }
        u16* dp = dst0 + ((size_t)(b_ * NH + hbase + hh) * S_LEN + s_) * HD + d0;
        *(bf16x8*)dp = r1;
        *(bf16x8*)(dp + 64) = r2;
      }
    } else {
      // V tile: transpose to Vt[B,H,D,S]
      const int hbase = (bn - 2 * HIDN) >> 7;
#pragma unroll
      for (int it = 0; it < 16; ++it) {
        const int idx = it * 512 + tid;                   // 32 s-chunks * 256 cols
        const int sc8 = idx >> 8, cl = idx & 255;
        const int s0 = sc8 * 8;
        bf16x8 v;
#pragma unroll
        for (int j = 0; j < 8; ++j) {
          const int rw = s0 + j;
          v[j] = __builtin_bit_cast(__bf16,
                 tile[rw * 256 + ((((cl >> 3) ^ (rw & 7)) << 3) | (cl & 7))]);
        }
        const int sg = bm + s0, b_ = sg >> 11, s_ = sg & 2047;
        const int h_ = hbase + (cl >> 7), d_ = cl & 127;
        *(bf16x8*)&Vo[((size_t)(b_ * NH + h_) * HD + d_) * S_LEN + s_] = v;
      }
    }
  }
}

// ---------------- causal flash attention: 8 waves/block, QBLK=128 ----------------
// 512 threads = 8 waves; wave w owns the 16 q-rows qb*128 + w*16 .. +16 (fully
// parallel waves — NOT R4's serial 2-tile-per-wave). KVBLK=64, K/V
// double-buffered + XOR-swizzled in LDS. Staging per q-row and barriers per
// q-row HALVED vs 4-wave version; LDS 80KB -> 2 blocks/CU = 16 waves/CU (2x
// TLP). Longest-first block remap (qb = 15 - (blk>>6)); exp2-domain softmax
// (log2e in Q); defer-max THR=8; causal n-block / PV-half skips; wave-uniform
// fully-masked-step guard (also prevents p=2^0 contamination).
__global__ __launch_bounds__(512) void attn_k(
    const u16* __restrict__ Q, const u16* __restrict__ K,
    const u16* __restrict__ Vt, u16* __restrict__ O) {
  __shared__ alignas(16) u16 kbuf[2][64 * 128];
  __shared__ alignas(16) u16 vbuf[2][128 * 64];
  __shared__ alignas(16) u16 plds[8][16 * 64];
  const int blk = blockIdx.x;
  const int qb = 15 - (blk >> 6);          // longest blocks dispatch first
  const int bhid = blk & 63;
  const int b = bhid >> 5, h = bhid & 31;
  const int tid = threadIdx.x;
  const int w = tid >> 6, l = tid & 63;
  const int lr = l & 15, lg = l >> 4;
  const size_t bh = (size_t)(b * NH + h);
  const u16* Qp = Q + (bh * S_LEN + (size_t)qb * 128 + (size_t)w * 16) * HD;
  const u16* Kp = K + bh * S_LEN * HD;
  const u16* Vp = Vt + bh * HD * S_LEN;

  bf16x8 qf[4];
#pragma unroll
  for (int kd = 0; kd < 4; ++kd)
    qf[kd] = *(const bf16x8*)&Qp[lr * HD + kd * 32 + lg * 8];

  f32x4 oacc[8] = {};
  float m[4], lsum[4];
#pragma unroll
  for (int r = 0; r < 4; ++r) { m[r] = -1e30f; lsum[r] = 0.f; }
  const int nsteps = 2 * qb + 2;
  const int qmin = qb * 128 + w * 16;      // wave-uniform first q row
  const int qmaxw = qmin + 15;
  const int qrow0 = qmin + lg * 4;

  // staging (512 threads): K 64x128 (2 loads/thr), V 128x64 (2 loads/thr);
  // source col pre-XOR'd (rule #21), linear LDS dest
#define ASTAGE(buf, kv0) do { \
    _Pragma("unroll") \
    for (int c = 0; c < 2; ++c) { \
      const int kr = c * 32 + (tid >> 4); \
      const int kc = ((tid & 15) * 8) ^ ((kr & 7) << 3); \
      gload16(Kp + (size_t)((kv0) + kr) * HD + kc, &kbuf[buf][c * 4096 + tid * 8]); \
      const int vr = c * 64 + (tid >> 3); \
      const int vc = ((tid & 7) * 8) ^ ((vr & 7) << 3); \
      gload16(Vp + (size_t)vr * S_LEN + (kv0) + vc, &vbuf[buf][c * 4096 + tid * 8]); \
    } \
  } while (0)

  ASTAGE(0, 0);
  for (int st = 0; st < nsteps; ++st) {
    const int kv0 = st * 64;
    const int cur = st & 1;
    __syncthreads();                       // stage(cur) landed; buf cur^1 free
    if (st + 1 < nsteps) ASTAGE(cur ^ 1, kv0 + 64);

    if (kv0 <= qmaxw) {                    // wave-uniform: skip fully-masked steps
      const int na0 = ((qmaxw - kv0) >> 4) + 1;
      const int na = na0 > 4 ? 4 : na0;    // active 16-col n-blocks (wave-uniform)

      // ---- QK^T (active n-blocks only) ----
      f32x4 sacc[4] = {};
      __builtin_amdgcn_s_setprio(1);
#pragma unroll
      for (int n = 0; n < 4; ++n) {
        if (n < na) {
          const int krow = n * 16 + lr;
          const int swzk = (krow & 7) << 3;
#pragma unroll
          for (int kd = 0; kd < 4; ++kd) {
            const bf16x8 kf = *(const bf16x8*)&kbuf[cur][krow * 128 + ((kd * 32 + lg * 8) ^ swzk)];
            sacc[n] = MFMA16(qf[kd], kf, sacc[n]);
          }
        }
      }
      __builtin_amdgcn_s_setprio(0);
      // ---- causal mask (skip when step fully below diagonal) ----
      float sv[4][4];
      if (kv0 + 63 <= qmin) {
#pragma unroll
        for (int n = 0; n < 4; ++n)
#pragma unroll
          for (int r = 0; r < 4; ++r) sv[n][r] = sacc[n][r];
      } else {
#pragma unroll
        for (int n = 0; n < 4; ++n) {
          const int col = kv0 + n * 16 + lr;
#pragma unroll
          for (int r = 0; r < 4; ++r)
            sv[n][r] = (col <= qrow0 + r) ? sacc[n][r] : -1e30f;
        }
      }
      // ---- row max + defer-max (THR=8 in exp2 domain) ----
      float vmx[4];
#pragma unroll
      for (int r = 0; r < 4; ++r) {
        float v = fmaxf(fmaxf(sv[0][r], sv[1][r]), fmaxf(sv[2][r], sv[3][r]));
#pragma unroll
        for (int off = 1; off < 16; off <<= 1)
          v = fmaxf(v, __shfl_xor(v, off, 16));
        vmx[r] = v;
      }
      bool ok = true;
#pragma unroll
      for (int r = 0; r < 4; ++r) ok &= (vmx[r] <= m[r] + 8.f);
      if (!__all(ok)) {
        float al[4];
#pragma unroll
        for (int r = 0; r < 4; ++r) {
          float mn = fmaxf(m[r], vmx[r]);
          al[r] = fexp2(m[r] - mn);
          m[r] = mn;
          lsum[r] *= al[r];
        }
#pragma unroll
        for (int db = 0; db < 8; ++db)
#pragma unroll
          for (int r = 0; r < 4; ++r)
            oacc[db][r] *= al[r];
      }
      // ---- P = 2^(sv-m), write to LDS, row-sum ----
#pragma unroll
      for (int r = 0; r < 4; ++r) {
        const int prow = lg * 4 + r;
        const int pswz = (prow & 7) << 3;
        float ps = 0.f;
#pragma unroll
        for (int n = 0; n < 4; ++n) {
          float p = fexp2(sv[n][r] - m[r]);
          plds[w][prow * 64 + ((n * 16 + lr) ^ pswz)] = f2bf(p);
          ps += p;
        }
#pragma unroll
        for (int off = 1; off < 16; off <<= 1)
          ps += __shfl_xor(ps, off, 16);
        lsum[r] += ps;
      }
      // ---- PV (skip fully-masked 32-col halves) ----
      __builtin_amdgcn_s_setprio(1);
#pragma unroll
      for (int ks = 0; ks < 2; ++ks) {
        if (kv0 + ks * 32 > qmaxw) continue;   // wave-uniform, P==0 there
        const bf16x8 pf = *(const bf16x8*)&plds[w][lr * 64 + ((ks * 32 + lg * 8) ^ ((lr & 7) << 3))];
#pragma unroll
        for (int db = 0; db < 8; ++db) {
          const int vrow = db * 16 + lr;
          const bf16x8 vf = *(const bf16x8*)&vbuf[cur][vrow * 64 + ((ks * 32 + lg * 8) ^ ((vrow & 7) << 3))];
          oacc[db] = MFMA16(pf, vf, oacc[db]);
        }
      }
      __builtin_amdgcn_s_setprio(0);
    }
  }
#undef ASTAGE

  u16* Op = O + ((size_t)b * S_LEN + (size_t)qb * 128 + (size_t)w * 16) * HIDN + h * HD;
#pragma unroll
  for (int db = 0; db < 8; ++db)
#pragma unroll
    for (int r = 0; r < 4; ++r)
      Op[(size_t)(lg * 4 + r) * HIDN + db * 16 + lr] = f2bf(oacc[db][r] / lsum[r]);
}

// ---------------- launcher ----------------
extern "C" void kernel_launch(void* const* d_in, const int* in_sizes, int n_in,
                              void* d_out, int out_size, void* d_ws, size_t ws_size,
                              hipStream_t stream) {
  const int*   positions = (const int*)d_in[0];
  const float* hidden    = (const float*)d_in[1];
  const float* Wqkv      = (const float*)d_in[2];
  const float* bqkv      = (const float*)d_in[3];
  const float* Wo        = (const float*)d_in[4];
  const float* bo        = (const float*)d_in[5];
  float* out = (float*)d_out;
  char* ws = (char*)d_ws;

  // workspace layout (bytes)
  u16*   WqkvT = (u16*)(ws + 0);            // [12288][4096] bf16, 96 MiB
  u16*   WoT   = (u16*)(ws + 100663296);    // [4096][4096] bf16, 32 MiB
  u16*   Xb    = (u16*)(ws + 134217728);    // [4096][4096] bf16, 32 MiB
  float* cosT  = (float*)(ws + 167772160);  // [2048][64] f32
  float* sinT  = (float*)(ws + 168296448);
  // Q/K/Vt written directly by GEMM1's fused epilogue
  u16* Qr  = (u16*)(ws + 168820736);        // 32 MiB
  u16* Kr  = Qr + 16777216;                 // 32 MiB
  u16* Vtr = Kr + 16777216;                 // 32 MiB
  u16* Ob  = Xb;                            // Xb dead after GEMM1

  transpose_cast<<<dim3(384, 128), dim3(32, 8), 0, stream>>>(Wqkv, WqkvT, 4096, 12288);
  transpose_cast<<<dim3(128, 128), dim3(32, 8), 0, stream>>>(Wo, WoT, 4096, 4096);
  cast_bf16_k<<<16384, 256, 0, stream>>>(hidden, Xb, 4194304);
  rope_table_k<<<512, 256, 0, stream>>>(positions, cosT, sinT);
  gemm256<1><<<768, 512, 0, stream>>>(Xb, WqkvT, bqkv, nullptr, 4096, 12288, 4096, 16,
                                      Qr, Kr, Vtr, cosT, sinT);
  attn_k<<<1024, 512, 0, stream>>>(Qr, Kr, Vtr, Ob);
  gemm256<0><<<256, 512, 0, stream>>>(Ob, WoT, bo, out, 4096, 4096, 4096, 16,
                                      nullptr, nullptr, nullptr, nullptr, nullptr);
}